// Round 2
// baseline (122.823 us; speedup 1.0000x reference)
//
#include <hip/hip_runtime.h>
#include <cstdint>
#include <cstddef>

#define WD  50
#define MT  256
#define BSZ 4096

__device__ __forceinline__ float swishf(float x) {
    // x * sigmoid(x) = x / (1 + exp(-x))
    return x / (1.0f + __expf(-x));
}

// One block = one (m, batch-chunk of 256). Lanes <-> batch elements, so all
// weight indices are wave-uniform -> scalar/broadcast loads feeding v_fmac.
// MODE 0: out[m*BSZ + b]           (workspace, coalesced; `out` pre-offset by branch)
// MODE 1: out[(b*MT + m)*2 + br]   (direct interleaved pairs, scattered)
// MODE 2: out[b*MT + m]            (direct single-float, scattered)
template<int MODE>
__global__ __launch_bounds__(256, 4) void rmat_mlp(
    const float* __restrict__ U,
    const float* __restrict__ W1, const float* __restrict__ B1,
    const float* __restrict__ W2, const float* __restrict__ B2,
    const float* __restrict__ W3, const float* __restrict__ B3,
    float* __restrict__ out, int br)
{
    const int m = blockIdx.x >> 4;                        // 0..255
    const int b = ((blockIdx.x & 15) << 8) | threadIdx.x; // 0..4095
    const float u = U[b];

    const float* __restrict__ w1 = W1 + m * WD;
    const float* __restrict__ b1 = B1 + m * WD;
    const float* __restrict__ w2 = W2 + (size_t)m * WD * WD;
    const float* __restrict__ b2 = B2 + m * WD;
    const float* __restrict__ w3 = W3 + m * WD;

    // Layer 1: h1[w] = swish(u*W1 + b1), all in registers (static indices).
    float h1[WD];
#pragma unroll
    for (int w = 0; w < WD; ++w)
        h1[w] = swishf(fmaf(u, w1[w], b1[w]));

    float acc = B3[m];

    // Layer 2+3 fused: 4 output neurons at a time -> 4 independent FMA chains.
#pragma unroll 1
    for (int v = 0; v < 48; v += 4) {
        float a0 = b2[v], a1 = b2[v + 1], a2 = b2[v + 2], a3 = b2[v + 3];
        const float* __restrict__ r0 = w2 + v * WD;
#pragma unroll
        for (int w = 0; w < WD; ++w) {
            const float h = h1[w];
            a0 = fmaf(r0[w],          h, a0);
            a1 = fmaf(r0[WD + w],     h, a1);
            a2 = fmaf(r0[2 * WD + w], h, a2);
            a3 = fmaf(r0[3 * WD + w], h, a3);
        }
        acc = fmaf(swishf(a0), w3[v],     acc);
        acc = fmaf(swishf(a1), w3[v + 1], acc);
        acc = fmaf(swishf(a2), w3[v + 2], acc);
        acc = fmaf(swishf(a3), w3[v + 3], acc);
    }
    {   // tail: v = 48, 49
        float a0 = b2[48], a1 = b2[49];
        const float* __restrict__ r0 = w2 + 48 * WD;
#pragma unroll
        for (int w = 0; w < WD; ++w) {
            const float h = h1[w];
            a0 = fmaf(r0[w],      h, a0);
            a1 = fmaf(r0[WD + w], h, a1);
        }
        acc = fmaf(swishf(a0), w3[48], acc);
        acc = fmaf(swishf(a1), w3[49], acc);
    }

    if (MODE == 0)      out[(size_t)m * BSZ + b] = acc;
    else if (MODE == 1) out[((size_t)b * MT + m) * 2 + br] = acc;
    else                out[(size_t)b * MT + m] = acc;
}

// ws[NBR][256][4096] -> out. NBR=2: complex interleave [b][m][re,im];
// NBR=1: transpose to [b][m]. Tile 32 m x 64 b through LDS.
template<int NBR>
__global__ __launch_bounds__(256) void rmat_interleave(
    const float* __restrict__ ws, float* __restrict__ out)
{
    __shared__ float tile[NBR][32][64 + 1];
    const int bt = blockIdx.x & 63;   // 64 b-tiles
    const int mt = blockIdx.x >> 6;   // 8 m-tiles
    const int b0 = bt * 64, m0 = mt * 32;

    for (int i = threadIdx.x; i < NBR * 32 * 64; i += 256) {
        const int br = i >> 11;        // 0 when NBR==1
        const int r  = (i >> 6) & 31;
        const int c  = i & 63;
        tile[br][r][c] = ws[(size_t)(br * MT + m0 + r) * BSZ + b0 + c];
    }
    __syncthreads();

    const int tb   = threadIdx.x >> 2;  // 0..63  (b within tile)
    const int part = threadIdx.x & 3;   // 0..3   (8 m each)
    const int b = b0 + tb;
    if (NBR == 2) {
        float2* __restrict__ dst =
            reinterpret_cast<float2*>(out) + (size_t)b * MT + m0 + part * 8;
#pragma unroll
        for (int k = 0; k < 8; ++k) {
            const int mm = part * 8 + k;
            dst[k] = make_float2(tile[0][mm][tb], tile[1][mm][tb]);
        }
    } else {
        float* __restrict__ dst = out + (size_t)b * MT + m0 + part * 8;
#pragma unroll
        for (int k = 0; k < 8; ++k)
            dst[k] = tile[0][part * 8 + k][tb];
    }
}

extern "C" void kernel_launch(void* const* d_in, const int* in_sizes, int n_in,
                              void* d_out, int out_size, void* d_ws, size_t ws_size,
                              hipStream_t stream) {
    const float* U   = (const float*)d_in[0];
    const float* W1r = (const float*)d_in[1];
    const float* b1r = (const float*)d_in[2];
    const float* W2r = (const float*)d_in[3];
    const float* b2r = (const float*)d_in[4];
    const float* W3r = (const float*)d_in[5];
    const float* b3r = (const float*)d_in[6];
    const float* W1i = (const float*)d_in[7];
    const float* b1i = (const float*)d_in[8];
    const float* W2i = (const float*)d_in[9];
    const float* b2i = (const float*)d_in[10];
    const float* W3i = (const float*)d_in[11];
    const float* b3i = (const float*)d_in[12];
    float* out = (float*)d_out;
    float* ws  = (float*)d_ws;

    const dim3 grid(MT * (BSZ / 256)), block(256);
    const size_t plane = (size_t)MT * BSZ;               // floats per branch

    if (out_size >= (int)(2 * plane)) {
        // d_out = [B][M] of (re,im) float pairs (complex64 viewed as f32 x2)
        if (ws_size >= 2 * plane * sizeof(float)) {
            rmat_mlp<0><<<grid, block, 0, stream>>>(U, W1r, b1r, W2r, b2r, W3r, b3r, ws, 0);
            rmat_mlp<0><<<grid, block, 0, stream>>>(U, W1i, b1i, W2i, b2i, W3i, b3i, ws + plane, 1);
            rmat_interleave<2><<<dim3(512), block, 0, stream>>>(ws, out);
        } else {
            rmat_mlp<1><<<grid, block, 0, stream>>>(U, W1r, b1r, W2r, b2r, W3r, b3r, out, 0);
            rmat_mlp<1><<<grid, block, 0, stream>>>(U, W1i, b1i, W2i, b2i, W3i, b3i, out, 1);
        }
    } else {
        // d_out holds only B*M float32 -> single component (real branch)
        if (ws_size >= plane * sizeof(float)) {
            rmat_mlp<0><<<grid, block, 0, stream>>>(U, W1r, b1r, W2r, b2r, W3r, b3r, ws, 0);
            rmat_interleave<1><<<dim3(512), block, 0, stream>>>(ws, out);
        } else {
            rmat_mlp<2><<<grid, block, 0, stream>>>(U, W1r, b1r, W2r, b2r, W3r, b3r, out, 0);
        }
    }
}

// Round 5
// 81.941 us; speedup vs baseline: 1.4989x; 1.4989x over previous
//
#include <hip/hip_runtime.h>
#include <cstdint>
#include <cstddef>

#define WD  50
#define MT  256
#define BSZ 4096
#define NCH 4                  // batch chunks per (m,branch)
#define BCH (BSZ / NCH)        // 1024 rows per block
#define ITERS (BCH / 4 / 16)   // 16 iters: per wave 256 rows, 16/iter

typedef short bf16x8 __attribute__((ext_vector_type(8)));
typedef float f32x4  __attribute__((ext_vector_type(4)));

__device__ __forceinline__ short f2bf(float x) {
    // RNE float -> bf16 bit pattern (no NaN handling needed for this data)
    union { float f; unsigned u; } c; c.f = x;
    const unsigned r = c.u + 0x7fffu + ((c.u >> 16) & 1u);
    return (short)(r >> 16);
}
__device__ __forceinline__ float swishf(float x) {
    return x / (1.0f + __expf(-x));   // R2-validated numerics
}

// Fused 1->50->50->1 MLP, layer-2 on bf16 MFMA (16x16x32), one branch.
// Block = (m, batch-chunk). 4 waves; each wave: 16 batch rows per iter.
// A (h1):  lane l -> row b=l&15,  k=(l>>4)*8+e  (computed in-register)
// B (W2^T):lane l -> col v=l&15,  k=(l>>4)*8+e  (static, 8 frags; k-perm
//          cancels between A and B since both use the same k map)
// D:       col v=l&15, row=(l>>4)*4+g           [m89-verified]
// MODE 0: out[m*BSZ + b]            (ws plane, caller pre-offsets by branch)
// MODE 1: out[(b*MT + m)*2 + br]    (direct interleaved pairs)
// MODE 2: out[b*MT + m]             (direct single-float)
template<int MODE>
__global__ __launch_bounds__(256, 4) void rmat_mlp_mfma(
    const float* __restrict__ U,
    const float* __restrict__ W1, const float* __restrict__ B1,
    const float* __restrict__ W2, const float* __restrict__ B2,
    const float* __restrict__ W3, const float* __restrict__ B3,
    float* __restrict__ out, int br)
{
    const int m  = blockIdx.x >> 2;        // 0..255
    const int ch = blockIdx.x & 3;         // 0..3

    const float* __restrict__ w1 = W1 + m * WD;
    const float* __restrict__ b1 = B1 + m * WD;
    const float* __restrict__ w2 = W2 + (size_t)m * WD * WD;
    const float* __restrict__ b2 = B2 + m * WD;
    const float* __restrict__ w3 = W3 + m * WD;
    const float  b3v = B3[m];

    const int lane = threadIdx.x & 63;
    const int wid  = threadIdx.x >> 6;
    const int lr   = lane & 15;            // A-row / D-col(v)
    const int lg   = lane >> 4;            // k-group / D-row-group

    // ---- static per-lane state (one-time prologue) ----
    bf16x8 wfrag[4][2];                    // W2^T: 4 v-tiles x 2 k-tiles
#pragma unroll
    for (int vt = 0; vt < 4; ++vt) {
        const int v = vt * 16 + lr;
#pragma unroll
        for (int kt = 0; kt < 2; ++kt)
#pragma unroll
            for (int e = 0; e < 8; ++e) {
                const int k = kt * 32 + lg * 8 + e;
                const float w = (v < WD && k < WD) ? w2[v * WD + k] : 0.0f;
                wfrag[vt][kt][e] = f2bf(w);
            }
    }
    float w1v[16], b1v[16];                // this lane's 16 k slots
#pragma unroll
    for (int kt = 0; kt < 2; ++kt)
#pragma unroll
        for (int e = 0; e < 8; ++e) {
            const int k = kt * 32 + lg * 8 + e;
            w1v[kt * 8 + e] = (k < WD) ? w1[k] : 0.0f;
            b1v[kt * 8 + e] = (k < WD) ? b1[k] : 0.0f;
        }
    float b2v[4], w3v[4];                  // this lane's v per v-tile
#pragma unroll
    for (int vt = 0; vt < 4; ++vt) {
        const int v = vt * 16 + lr;
        b2v[vt] = (v < WD) ? b2[v] : 0.0f;
        w3v[vt] = (v < WD) ? w3[v] : 0.0f;
    }

    float* __restrict__ dst = out + (size_t)m * BSZ;   // MODE 0 base
    const int b0 = ch * BCH + wid * (BCH / 4);         // wave's 256-row slice

#pragma unroll 1
    for (int it = 0; it < ITERS; ++it) {
        const int bb = b0 + it * 16;
        const float u = U[bb + lr];

        // layer 1 -> A fragments (bf16 bits in shorts)
        bf16x8 a0, a1;
#pragma unroll
        for (int e = 0; e < 8; ++e)
            a0[e] = f2bf(swishf(fmaf(u, w1v[e], b1v[e])));
#pragma unroll
        for (int e = 0; e < 8; ++e)
            a1[e] = f2bf(swishf(fmaf(u, w1v[8 + e], b1v[8 + e])));

        // layer 2 on the matrix pipe: 4 v-tiles x K=64
        f32x4 acc[4];
#pragma unroll
        for (int vt = 0; vt < 4; ++vt) {
            acc[vt] = (f32x4){0.f, 0.f, 0.f, 0.f};
            acc[vt] = __builtin_amdgcn_mfma_f32_16x16x32_bf16(a0, wfrag[vt][0], acc[vt], 0, 0, 0);
            acc[vt] = __builtin_amdgcn_mfma_f32_16x16x32_bf16(a1, wfrag[vt][1], acc[vt], 0, 0, 0);
        }

        // layer 3: swish + w3 dot, reduce across the 16 v-lanes
        float part[4];
#pragma unroll
        for (int g = 0; g < 4; ++g) {
            float p = 0.0f;
#pragma unroll
            for (int vt = 0; vt < 4; ++vt)
                p = fmaf(swishf(acc[vt][g] + b2v[vt]), w3v[vt], p);
            part[g] = p;
        }
#pragma unroll
        for (int g = 0; g < 4; ++g) {
            part[g] += __shfl_xor(part[g], 1);
            part[g] += __shfl_xor(part[g], 2);
            part[g] += __shfl_xor(part[g], 4);
            part[g] += __shfl_xor(part[g], 8);
        }

        if (lr == 0) {
            const int row = bb + lg * 4;
            if (MODE == 0) {
                *reinterpret_cast<float4*>(dst + row) =
                    make_float4(part[0] + b3v, part[1] + b3v,
                                part[2] + b3v, part[3] + b3v);
            } else if (MODE == 1) {
#pragma unroll
                for (int g = 0; g < 4; ++g)
                    out[((size_t)(row + g) * MT + m) * 2 + br] = part[g] + b3v;
            } else {
#pragma unroll
                for (int g = 0; g < 4; ++g)
                    out[(size_t)(row + g) * MT + m] = part[g] + b3v;
            }
        }
    }
}

// ws[NBR][256][4096] -> out. NBR=2: [b][m][re,im]; NBR=1: transpose to [b][m].
// (Verbatim from the round-2 PASS.)
template<int NBR>
__global__ __launch_bounds__(256) void rmat_interleave(
    const float* __restrict__ ws, float* __restrict__ out)
{
    __shared__ float tile[NBR][32][64 + 1];
    const int bt = blockIdx.x & 63;
    const int mt = blockIdx.x >> 6;
    const int b0 = bt * 64, m0 = mt * 32;

    for (int i = threadIdx.x; i < NBR * 32 * 64; i += 256) {
        const int brx = i >> 11;           // 0 when NBR==1
        const int r   = (i >> 6) & 31;
        const int c   = i & 63;
        tile[brx][r][c] = ws[(size_t)(brx * MT + m0 + r) * BSZ + b0 + c];
    }
    __syncthreads();

    const int tb   = threadIdx.x >> 2;
    const int part = threadIdx.x & 3;
    const int b = b0 + tb;
    if (NBR == 2) {
        float2* __restrict__ dstp =
            reinterpret_cast<float2*>(out) + (size_t)b * MT + m0 + part * 8;
#pragma unroll
        for (int k = 0; k < 8; ++k) {
            const int mm = part * 8 + k;
            dstp[k] = make_float2(tile[0][mm][tb], tile[1][mm][tb]);
        }
    } else {
        float* __restrict__ dstp = out + (size_t)b * MT + m0 + part * 8;
#pragma unroll
        for (int k = 0; k < 8; ++k)
            dstp[k] = tile[0][part * 8 + k][tb];
    }
}

extern "C" void kernel_launch(void* const* d_in, const int* in_sizes, int n_in,
                              void* d_out, int out_size, void* d_ws, size_t ws_size,
                              hipStream_t stream) {
    const float* U   = (const float*)d_in[0];
    const float* W1r = (const float*)d_in[1];
    const float* b1r = (const float*)d_in[2];
    const float* W2r = (const float*)d_in[3];
    const float* b2r = (const float*)d_in[4];
    const float* W3r = (const float*)d_in[5];
    const float* b3r = (const float*)d_in[6];
    const float* W1i = (const float*)d_in[7];
    const float* b1i = (const float*)d_in[8];
    const float* W2i = (const float*)d_in[9];
    const float* b2i = (const float*)d_in[10];
    const float* W3i = (const float*)d_in[11];
    const float* b3i = (const float*)d_in[12];
    float* out = (float*)d_out;
    float* ws  = (float*)d_ws;

    const dim3 grid(MT * NCH), block(256);
    const size_t plane = (size_t)MT * BSZ;   // floats per branch

    if (out_size >= (int)(2 * plane)) {
        // d_out = [B][M] of (re,im) float pairs
        if (ws_size >= 2 * plane * sizeof(float)) {
            rmat_mlp_mfma<0><<<grid, block, 0, stream>>>(U, W1r, b1r, W2r, b2r, W3r, b3r, ws, 0);
            rmat_mlp_mfma<0><<<grid, block, 0, stream>>>(U, W1i, b1i, W2i, b2i, W3i, b3i, ws + plane, 1);
            rmat_interleave<2><<<dim3(512), block, 0, stream>>>(ws, out);
        } else {
            rmat_mlp_mfma<1><<<grid, block, 0, stream>>>(U, W1r, b1r, W2r, b2r, W3r, b3r, out, 0);
            rmat_mlp_mfma<1><<<grid, block, 0, stream>>>(U, W1i, b1i, W2i, b2i, W3i, b3i, out, 1);
        }
    } else {
        // d_out holds B*M float32 -> real branch only (harness drops imag)
        if (ws_size >= plane * sizeof(float)) {
            rmat_mlp_mfma<0><<<grid, block, 0, stream>>>(U, W1r, b1r, W2r, b2r, W3r, b3r, ws, 0);
            rmat_interleave<1><<<dim3(512), block, 0, stream>>>(ws, out);
        } else {
            rmat_mlp_mfma<2><<<grid, block, 0, stream>>>(U, W1r, b1r, W2r, b2r, W3r, b3r, out, 0);
        }
    }
}

// Round 6
// 52.846 us; speedup vs baseline: 2.3242x; 1.5506x over previous
//
#include <hip/hip_runtime.h>
#include <cstdint>
#include <cstddef>

#define WD  50
#define MT  256
#define BSZ 4096
#define NCH 4                  // batch chunks per (m,branch)
#define BCH (BSZ / NCH)        // 1024 rows per block
#define ITERS (BCH / 4 / 16)   // 16 iters: per wave 256 rows, 16/iter

typedef __bf16 bf16x8 __attribute__((ext_vector_type(8)));
typedef float  f32x4  __attribute__((ext_vector_type(4)));

__device__ __forceinline__ float swishf(float x) {
    // x * sigmoid(x) via v_rcp_f32 (rel err ~1e-5, noise vs bf16 rounding)
    return x * __builtin_amdgcn_rcpf(1.0f + __expf(-x));
}

// Fused 1->50->50->1 MLP, layer-2 on bf16 MFMA (16x16x32), one branch.
// Block = (m, batch-chunk). 4 waves; each wave: 16 batch rows per iter.
// A (h1):  lane l -> row b=l&15,  k=(l>>4)*8+e  (computed in-register)
// B (W2^T):lane l -> col v=l&15,  k=(l>>4)*8+e  (static, 8 frags; k-perm
//          cancels between A and B since both use the same k map)
// D:       col v=l&15, row=(l>>4)*4+g           [m89-verified]
// MODE 0: out[m*BSZ + b]            (ws plane, caller pre-offsets by branch)
// MODE 1: out[(b*MT + m)*2 + br]    (direct interleaved pairs)
// MODE 2: out[b*MT + m]             (direct single-float)
template<int MODE>
__global__ __launch_bounds__(256, 4) void rmat_mlp_mfma(
    const float* __restrict__ U,
    const float* __restrict__ W1, const float* __restrict__ B1,
    const float* __restrict__ W2, const float* __restrict__ B2,
    const float* __restrict__ W3, const float* __restrict__ B3,
    float* __restrict__ out, int br)
{
    const int m  = blockIdx.x >> 2;        // 0..255
    const int ch = blockIdx.x & 3;         // 0..3

    const float* __restrict__ w1 = W1 + m * WD;
    const float* __restrict__ b1 = B1 + m * WD;
    const float* __restrict__ w2 = W2 + (size_t)m * WD * WD;
    const float* __restrict__ b2 = B2 + m * WD;
    const float* __restrict__ w3 = W3 + m * WD;
    const float  b3v = B3[m];

    const int lane = threadIdx.x & 63;
    const int wid  = threadIdx.x >> 6;
    const int lr   = lane & 15;            // A-row / D-col(v)
    const int lg   = lane >> 4;            // k-group / D-row-group

    // ---- static per-lane state (one-time prologue) ----
    bf16x8 wfrag[4][2];                    // W2^T: 4 v-tiles x 2 k-tiles
#pragma unroll
    for (int vt = 0; vt < 4; ++vt) {
        const int v = vt * 16 + lr;
#pragma unroll
        for (int kt = 0; kt < 2; ++kt)
#pragma unroll
            for (int e = 0; e < 8; ++e) {
                const int k = kt * 32 + lg * 8 + e;
                const float w = (v < WD && k < WD) ? w2[v * WD + k] : 0.0f;
                wfrag[vt][kt][e] = (__bf16)w;
            }
    }
    float w1v[16], b1v[16];                // this lane's 16 k slots
#pragma unroll
    for (int kt = 0; kt < 2; ++kt)
#pragma unroll
        for (int e = 0; e < 8; ++e) {
            const int k = kt * 32 + lg * 8 + e;
            w1v[kt * 8 + e] = (k < WD) ? w1[k] : 0.0f;
            b1v[kt * 8 + e] = (k < WD) ? b1[k] : 0.0f;
        }
    float b2v[4], w3v[4];                  // this lane's v per v-tile
#pragma unroll
    for (int vt = 0; vt < 4; ++vt) {
        const int v = vt * 16 + lr;
        b2v[vt] = (v < WD) ? b2[v] : 0.0f;
        w3v[vt] = (v < WD) ? w3[v] : 0.0f;
    }

    float* __restrict__ dst = out + (size_t)m * BSZ;   // MODE 0 base
    const int b0 = ch * BCH + wid * (BCH / 4);         // wave's 256-row slice

#pragma unroll 1
    for (int it = 0; it < ITERS; ++it) {
        const int bb = b0 + it * 16;
        const float u = U[bb + lr];

        // layer 1 -> A fragments; scalar (__bf16) casts pair into cvt_pk
        bf16x8 a0, a1;
#pragma unroll
        for (int e = 0; e < 8; ++e)
            a0[e] = (__bf16)swishf(fmaf(u, w1v[e], b1v[e]));
#pragma unroll
        for (int e = 0; e < 8; ++e)
            a1[e] = (__bf16)swishf(fmaf(u, w1v[8 + e], b1v[8 + e]));

        // layer 2 on the matrix pipe: 4 v-tiles x K=64
        f32x4 acc[4];
#pragma unroll
        for (int vt = 0; vt < 4; ++vt) {
            acc[vt] = (f32x4){0.f, 0.f, 0.f, 0.f};
            acc[vt] = __builtin_amdgcn_mfma_f32_16x16x32_bf16(a0, wfrag[vt][0], acc[vt], 0, 0, 0);
            acc[vt] = __builtin_amdgcn_mfma_f32_16x16x32_bf16(a1, wfrag[vt][1], acc[vt], 0, 0, 0);
        }

        // layer 3: swish + w3 dot, reduce across the 16 v-lanes
        float part[4];
#pragma unroll
        for (int g = 0; g < 4; ++g) {
            float p = 0.0f;
#pragma unroll
            for (int vt = 0; vt < 4; ++vt)
                p = fmaf(swishf(acc[vt][g] + b2v[vt]), w3v[vt], p);
            part[g] = p;
        }
#pragma unroll
        for (int g = 0; g < 4; ++g) {
            part[g] += __shfl_xor(part[g], 1);
            part[g] += __shfl_xor(part[g], 2);
            part[g] += __shfl_xor(part[g], 4);
            part[g] += __shfl_xor(part[g], 8);
        }

        if (lr == 0) {
            const int row = bb + lg * 4;
            if (MODE == 0) {
                *reinterpret_cast<float4*>(dst + row) =
                    make_float4(part[0] + b3v, part[1] + b3v,
                                part[2] + b3v, part[3] + b3v);
            } else if (MODE == 1) {
#pragma unroll
                for (int g = 0; g < 4; ++g)
                    out[((size_t)(row + g) * MT + m) * 2 + br] = part[g] + b3v;
            } else {
#pragma unroll
                for (int g = 0; g < 4; ++g)
                    out[(size_t)(row + g) * MT + m] = part[g] + b3v;
            }
        }
    }
}

// ws[NBR][256][4096] -> out. NBR=2: [b][m][re,im]; NBR=1: transpose to [b][m].
// (Verbatim from the round-2/5 PASS.)
template<int NBR>
__global__ __launch_bounds__(256) void rmat_interleave(
    const float* __restrict__ ws, float* __restrict__ out)
{
    __shared__ float tile[NBR][32][64 + 1];
    const int bt = blockIdx.x & 63;
    const int mt = blockIdx.x >> 6;
    const int b0 = bt * 64, m0 = mt * 32;

    for (int i = threadIdx.x; i < NBR * 32 * 64; i += 256) {
        const int brx = i >> 11;           // 0 when NBR==1
        const int r   = (i >> 6) & 31;
        const int c   = i & 63;
        tile[brx][r][c] = ws[(size_t)(brx * MT + m0 + r) * BSZ + b0 + c];
    }
    __syncthreads();

    const int tb   = threadIdx.x >> 2;
    const int part = threadIdx.x & 3;
    const int b = b0 + tb;
    if (NBR == 2) {
        float2* __restrict__ dstp =
            reinterpret_cast<float2*>(out) + (size_t)b * MT + m0 + part * 8;
#pragma unroll
        for (int k = 0; k < 8; ++k) {
            const int mm = part * 8 + k;
            dstp[k] = make_float2(tile[0][mm][tb], tile[1][mm][tb]);
        }
    } else {
        float* __restrict__ dstp = out + (size_t)b * MT + m0 + part * 8;
#pragma unroll
        for (int k = 0; k < 8; ++k)
            dstp[k] = tile[0][part * 8 + k][tb];
    }
}

extern "C" void kernel_launch(void* const* d_in, const int* in_sizes, int n_in,
                              void* d_out, int out_size, void* d_ws, size_t ws_size,
                              hipStream_t stream) {
    const float* U   = (const float*)d_in[0];
    const float* W1r = (const float*)d_in[1];
    const float* b1r = (const float*)d_in[2];
    const float* W2r = (const float*)d_in[3];
    const float* b2r = (const float*)d_in[4];
    const float* W3r = (const float*)d_in[5];
    const float* b3r = (const float*)d_in[6];
    const float* W1i = (const float*)d_in[7];
    const float* b1i = (const float*)d_in[8];
    const float* W2i = (const float*)d_in[9];
    const float* b2i = (const float*)d_in[10];
    const float* W3i = (const float*)d_in[11];
    const float* b3i = (const float*)d_in[12];
    float* out = (float*)d_out;
    float* ws  = (float*)d_ws;

    const dim3 grid(MT * NCH), block(256);
    const size_t plane = (size_t)MT * BSZ;   // floats per branch

    if (out_size >= (int)(2 * plane)) {
        // d_out = [B][M] of (re,im) float pairs
        if (ws_size >= 2 * plane * sizeof(float)) {
            rmat_mlp_mfma<0><<<grid, block, 0, stream>>>(U, W1r, b1r, W2r, b2r, W3r, b3r, ws, 0);
            rmat_mlp_mfma<0><<<grid, block, 0, stream>>>(U, W1i, b1i, W2i, b2i, W3i, b3i, ws + plane, 1);
            rmat_interleave<2><<<dim3(512), block, 0, stream>>>(ws, out);
        } else {
            rmat_mlp_mfma<1><<<grid, block, 0, stream>>>(U, W1r, b1r, W2r, b2r, W3r, b3r, out, 0);
            rmat_mlp_mfma<1><<<grid, block, 0, stream>>>(U, W1i, b1i, W2i, b2i, W3i, b3i, out, 1);
        }
    } else {
        // d_out holds B*M float32 -> real branch only (harness drops imag)
        if (ws_size >= plane * sizeof(float)) {
            rmat_mlp_mfma<0><<<grid, block, 0, stream>>>(U, W1r, b1r, W2r, b2r, W3r, b3r, ws, 0);
            rmat_interleave<1><<<dim3(512), block, 0, stream>>>(ws, out);
        } else {
            rmat_mlp_mfma<2><<<grid, block, 0, stream>>>(U, W1r, b1r, W2r, b2r, W3r, b3r, out, 0);
        }
    }
}